// Round 1
// baseline (243.267 us; speedup 1.0000x reference)
//
#include <hip/hip_runtime.h>
#include <hip/hip_bf16.h>
#include <cstdint>
#include <cstddef>

// ---------------------------------------------------------------------------
// DebugBertLayer: reference overwrites q,k,v with 0.01 AFTER the projections,
// so ctx == 0.01 and ctx @ Wo.T + bo collapses to a per-channel constant
// c[i] = 0.01 * rowsum(Wo)[i] + bo[i].  Real work:
//   LN1(hidden + c) -> GEMM1(+GELU) -> GEMM2 (split-K=2) -> LN2(combine).
// R9: GEMMs rewritten from the 128^2 2-barrier (m97) structure (MfmaUtil 28%)
// to the 256^2 8-phase counted-vmcnt template (m201 lineage):
//   - 8 waves (2Mx4N), per-wave 128x64 output, mfma_f32_16x16x32_bf16
//   - 128 KiB LDS: per matrix a ring of 4 chunk-slots (256 rows x 32 K bf16)
//   - staging via global_load_lds(16B), linear LDS dest, inverse-XOR-swizzled
//     global source; ds_read side applies the same XOR -> ~conflict-free
//   - 4 phases per K-tile {dsread | stage-issue | bar | lgkmcnt(0) | 16 MFMA |
//     bar}, chunk issue LEAD=6, ONE s_waitcnt vmcnt(4) per K-tile (drain only
//     for the final two tiles) -> loads stay in flight across barriers
//   - s_setprio(1) around MFMA clusters (T5; pays only with phase-split)
//   - epilogue: operand-swapped MFMA => D transposed => per-lane 4 contiguous
//     N-elems, direct bf16x4 global stores (no LDS round-trip)
// ---------------------------------------------------------------------------

typedef __bf16 bf16;
typedef __attribute__((ext_vector_type(8))) __bf16 bf16x8;
typedef __attribute__((ext_vector_type(4))) __bf16 bf16x4;
typedef __attribute__((ext_vector_type(4))) float  floatx4;

#define DM    768      // d_model
#define DF    3072     // d_ff
#define MROWS 8192     // B*S = 4*2048

#define N8          (DF * DM / 8)          // 294912 : 8-elem groups per weight
#define CONV_BLOCKS (2 * N8 / 256)         // 2304 convert blocks
#define CVEC_BLOCKS (DM / 4)               // 192 blocks, wave per row

__device__ __forceinline__ void gl2lds16(const void* gp, void* lp) {
  __builtin_amdgcn_global_load_lds(
      (__attribute__((address_space(1))) void*)(void*)gp,
      (__attribute__((address_space(3))) void*)lp,
      16, 0, 0);
}

// fast GELU (tanh form): x * sigmoid(1.5958*(x + 0.044715*x^3))
__device__ __forceinline__ float gelu_fast(float x) {
  float x2 = x * x;
  float m  = x * __builtin_fmaf(-0.1029641f, x2, -2.3025851f);
  float e  = __builtin_amdgcn_exp2f(m);
  return x * __builtin_amdgcn_rcpf(1.0f + e);
}

// ---------------------------------------------------------------------------
// prep: blocks [0, CONV_BLOCKS) convert Wi/Wf fp32->bf16 (8 elem/thread);
//       blocks [CONV_BLOCKS, +CVEC_BLOCKS) compute cvec, one wave per row.
// ---------------------------------------------------------------------------
__global__ __launch_bounds__(256)
void prep_kernel(const float* __restrict__ Wi, const float* __restrict__ Wf,
                 bf16* __restrict__ Wib, bf16* __restrict__ Wfb,
                 const float* __restrict__ Wo, const float* __restrict__ bo,
                 float* __restrict__ cvec) {
  if (blockIdx.x < CONV_BLOCKS) {
    int i = blockIdx.x * 256 + threadIdx.x;
    const float* src = (i < N8) ? Wi : Wf;
    bf16* dst        = (i < N8) ? Wib : Wfb;
    int k            = (i < N8) ? i : i - N8;
    const float4* p = (const float4*)(src + (size_t)k * 8);
    float4 x = p[0], y = p[1];
    bf16x8 o;
    o[0]=(bf16)x.x; o[1]=(bf16)x.y; o[2]=(bf16)x.z; o[3]=(bf16)x.w;
    o[4]=(bf16)y.x; o[5]=(bf16)y.y; o[6]=(bf16)y.z; o[7]=(bf16)y.w;
    *(bf16x8*)(dst + (size_t)k * 8) = o;
  } else {
    int row  = (blockIdx.x - CONV_BLOCKS) * 4 + (threadIdx.x >> 6);
    int lane = threadIdx.x & 63;
    const float4* r = (const float4*)(Wo + (size_t)row * DM);
    float s = 0.f;
    #pragma unroll
    for (int t = 0; t < 3; ++t) {
      float4 v = r[lane + t * 64];
      s += v.x + v.y + v.z + v.w;
    }
    #pragma unroll
    for (int o = 32; o > 0; o >>= 1) s += __shfl_xor(s, o);
    if (lane == 0) cvec[row] = 0.01f * s + bo[row];
  }
}

// ---------------------------------------------------------------------------
// attn_out[row] = LN(hidden[row] + cvec) -> bf16.  4 rows/block (wave each).
// ---------------------------------------------------------------------------
__global__ __launch_bounds__(256)
void ln1_kernel(const float* __restrict__ hid, const float* __restrict__ cvec,
                const float* __restrict__ g, const float* __restrict__ b,
                bf16* __restrict__ out) {
  int row  = blockIdx.x * 4 + (threadIdx.x >> 6);
  int lane = threadIdx.x & 63;
  const float4* hrow = (const float4*)(hid + (size_t)row * DM);
  const float4* cv4  = (const float4*)cvec;
  float x[12];
  float s = 0.f, sq = 0.f;
  #pragma unroll
  for (int t = 0; t < 3; ++t) {
    int c = lane + t * 64;
    float4 v = hrow[c];
    float4 cc = cv4[c];
    float x0 = v.x + cc.x, x1 = v.y + cc.y, x2 = v.z + cc.z, x3 = v.w + cc.w;
    x[t*4+0] = x0; x[t*4+1] = x1; x[t*4+2] = x2; x[t*4+3] = x3;
    s  += x0 + x1 + x2 + x3;
    sq += x0*x0 + x1*x1 + x2*x2 + x3*x3;
  }
  #pragma unroll
  for (int o = 32; o > 0; o >>= 1) { s += __shfl_xor(s, o); sq += __shfl_xor(sq, o); }
  float mu  = s * (1.0f / DM);
  float var = sq * (1.0f / DM) - mu * mu;
  float inv = rsqrtf(var + 1e-12f);
  const float4* g4 = (const float4*)g;
  const float4* b4 = (const float4*)b;
  #pragma unroll
  for (int t = 0; t < 3; ++t) {
    int c = lane + t * 64;
    float4 gg = g4[c], bb = b4[c];
    bf16x4 o4;
    o4[0] = (bf16)((x[t*4+0] - mu) * inv * gg.x + bb.x);
    o4[1] = (bf16)((x[t*4+1] - mu) * inv * gg.y + bb.y);
    o4[2] = (bf16)((x[t*4+2] - mu) * inv * gg.z + bb.z);
    o4[3] = (bf16)((x[t*4+3] - mu) * inv * gg.w + bb.w);
    *(bf16x4*)(out + (size_t)row * DM + c * 4) = o4;
  }
}

// ---------------------------------------------------------------------------
// out[row] = LN( p0 + p1 + bias + attn )   (bf16 partials) -> fp32 out
// ---------------------------------------------------------------------------
__global__ __launch_bounds__(256)
void ln2_kernel(const bf16* __restrict__ p0, const bf16* __restrict__ p1,
                const float* __restrict__ bias, const bf16* __restrict__ attn,
                const float* __restrict__ g, const float* __restrict__ b,
                float* __restrict__ out) {
  int row  = blockIdx.x * 4 + (threadIdx.x >> 6);
  int lane = threadIdx.x & 63;
  const bf16* r0 = p0 + (size_t)row * DM;
  const bf16* r1 = p1 + (size_t)row * DM;
  const bf16* ar = attn + (size_t)row * DM;
  const float4* bi4 = (const float4*)bias;
  float x[12];
  float s = 0.f, sq = 0.f;
  #pragma unroll
  for (int t = 0; t < 3; ++t) {
    int c = lane + t * 64;
    bf16x4 a = *(const bf16x4*)(r0 + c * 4);
    bf16x4 d = *(const bf16x4*)(r1 + c * 4);
    bf16x4 rv = *(const bf16x4*)(ar + c * 4);
    float4 bb = bi4[c];
    float x0 = (float)a[0] + (float)d[0] + bb.x + (float)rv[0];
    float x1 = (float)a[1] + (float)d[1] + bb.y + (float)rv[1];
    float x2 = (float)a[2] + (float)d[2] + bb.z + (float)rv[2];
    float x3 = (float)a[3] + (float)d[3] + bb.w + (float)rv[3];
    x[t*4+0] = x0; x[t*4+1] = x1; x[t*4+2] = x2; x[t*4+3] = x3;
    s  += x0 + x1 + x2 + x3;
    sq += x0*x0 + x1*x1 + x2*x2 + x3*x3;
  }
  #pragma unroll
  for (int o = 32; o > 0; o >>= 1) { s += __shfl_xor(s, o); sq += __shfl_xor(sq, o); }
  float mu  = s * (1.0f / DM);
  float var = sq * (1.0f / DM) - mu * mu;
  float inv = rsqrtf(var + 1e-12f);
  const float4* g4 = (const float4*)g;
  const float4* b4 = (const float4*)b;
  float4* orow = (float4*)(out + (size_t)row * DM);
  #pragma unroll
  for (int t = 0; t < 3; ++t) {
    int c = lane + t * 64;
    float4 gg = g4[c], bb = b4[c];
    float4 o;
    o.x = (x[t*4+0] - mu) * inv * gg.x + bb.x;
    o.y = (x[t*4+1] - mu) * inv * gg.y + bb.y;
    o.z = (x[t*4+2] - mu) * inv * gg.z + bb.z;
    o.w = (x[t*4+3] - mu) * inv * gg.w + bb.w;
    orow[c] = o;
  }
}

// ---------------------------------------------------------------------------
// 256x256 8-phase NT bf16 GEMM (m201-template).  8 waves (2Mx4N), per-wave
// 128x64 via mfma_f32_16x16x32_bf16 (operands swapped -> D transposed so the
// epilogue stores 4 contiguous N-elems per lane).
//
// LDS (131072 B): A-chunk ring  smem + slot*16384        (slot 0..3)
//                 B-chunk ring  smem + 65536 + slot*16384
// chunk = 256 rows x 32 K bf16 = 16 KiB, stream index a = 2*tile + ks,
// slot = a & 3.  Global chunk stream c = 4t + {0:A ks0, 1:B ks0, 2:A ks1,
// 3:B ks1}; phase q of tile t issues chunk 4t+q+6 (LEAD=6; slot of the
// overwritten chunk is provably free at that phase).  One vmcnt(4) per
// K-tile (last phase, before its closing barrier) keeps 2 chunks in flight;
// vmcnt(0) for t >= NT-2 (late issues are guarded out).
//
// Swizzle (rule 21, both-sides): logical kgroup kg at row r lives at
// physical kgroup kg ^ ((r>>1)&3).  Staging writes linear LDS and applies
// the inverse permutation to the *global* source column; ds_read applies
// the same XOR -> fragment reads hit 8 distinct 4-bank groups (2-way, free).
// ---------------------------------------------------------------------------
template <int EPI>   // 0: +bias +GELU (GEMM1)   1: raw partial (GEMM2 split-K)
__global__ __launch_bounds__(512, 2)
void gemm8p(const bf16* __restrict__ A, const bf16* __restrict__ B,
            const float* __restrict__ bias, bf16* __restrict__ out,
            int M, int N, int K, int ksplit, int NB, int CPX) {
  extern __shared__ char smem[];

  const int tid  = threadIdx.x;
  const int lane = tid & 63;
  const int wid  = tid >> 6;
  const int wm   = (wid >> 2) * 128;   // wave M-offset (2 waves in M)
  const int wn   = (wid & 3) * 64;     // wave N-offset (4 waves in N)
  const int l15  = lane & 15;
  const int kg   = lane >> 4;          // 8-elem k-group of the fragment

  // XCD-aware bijective remap (grid % 8 == 0 in both uses)
  const int wg = ((int)blockIdx.x & 7) * CPX + ((int)blockIdx.x >> 3);
  int mb, nb, zb;
  if constexpr (EPI == 0) { mb = wg / NB; nb = wg % NB; zb = 0; }
  else { mb = wg / (2 * NB); int r = wg % (2 * NB); nb = r % NB; zb = r / NB; }

  const int m0 = mb * 256, n0 = nb * 256;
  const int NT = ksplit >> 6;          // K-tiles of 64
  const bf16* Ab = A + (size_t)m0 * K + (size_t)zb * ksplit;
  const bf16* Bb = B + (size_t)n0 * K + (size_t)zb * ksplit;

  // per-thread staging geometry: 2 x global_load_lds(16B) per 16 KiB chunk
  const int r0s = tid >> 2;            // load0 rows 0..127
  const int r1s = 128 + (tid >> 2);    // load1 rows 128..255
  const int kgp = tid & 3;
  const int sw0 = (kgp ^ ((r0s >> 1) & 3)) << 3;  // inverse-swizzled elem off
  const int sw1 = (kgp ^ ((r1s >> 1) & 3)) << 3;
  const int d0  = tid * 16;            // linear LDS byte dest (lane-stride 16)
  const int d1  = (512 + tid) * 16;

  auto stage = [&](int c) {            // c: global chunk stream index
    if (c >= 4 * NT) return;
    const int tc = c >> 2, p = c & 3, ks = p >> 1, isB = p & 1;
    const int slot = (2 * tc + ks) & 3;
    char* base = smem + (isB ? 65536 : 0) + slot * 16384;
    const bf16* src = isB ? Bb : Ab;
    const int gk = tc * 64 + ks * 32;
    gl2lds16(src + (size_t)r0s * K + gk + sw0, base + d0);
    gl2lds16(src + (size_t)r1s * K + gk + sw1, base + d1);
  };

  // fragment read offsets (bytes within a chunk slot); swizzle matches stage
  int offA[8], offB[4];
  #pragma unroll
  for (int mf = 0; mf < 8; ++mf) {
    int r = wm + mf * 16 + l15;
    offA[mf] = r * 64 + ((kg ^ ((r >> 1) & 3)) << 4);
  }
  #pragma unroll
  for (int nf = 0; nf < 4; ++nf) {
    int r = wn + nf * 16 + l15;
    offB[nf] = 65536 + r * 64 + ((kg ^ ((r >> 1) & 3)) << 4);
  }

  floatx4 acc[8][4] = {};

  // prologue: chunks 0..5 = tile0 (all 4) + tile1 (A_k0,B_k0)
  #pragma unroll
  for (int c = 0; c < 6; ++c) stage(c);
  asm volatile("s_waitcnt vmcnt(4)" ::: "memory");  // chunks 0..3 landed
  __builtin_amdgcn_s_barrier();

  for (int t = 0; t < NT; ++t) {
    const int s2t = 2 * t;
    #pragma unroll
    for (int ks = 0; ks < 2; ++ks) {
      const int slot = (s2t + ks) & 3;
      char* sbase = smem + slot * 16384;

      // ---- phase ch=0: read A mf0..3 + all B, compute acc[0..3][*] ----
      bf16x8 af[4], bq[4];
      #pragma unroll
      for (int i = 0; i < 4; ++i) af[i] = *(const bf16x8*)(sbase + offA[i]);
      #pragma unroll
      for (int j = 0; j < 4; ++j) bq[j] = *(const bf16x8*)(sbase + offB[j]);
      stage(4 * t + 2 * ks + 6);
      __builtin_amdgcn_s_barrier();
      asm volatile("s_waitcnt lgkmcnt(0)" ::: "memory");
      __builtin_amdgcn_sched_barrier(0);
      __builtin_amdgcn_s_setprio(1);
      #pragma unroll
      for (int i = 0; i < 4; ++i)
        #pragma unroll
        for (int j = 0; j < 4; ++j)
          acc[i][j] = __builtin_amdgcn_mfma_f32_16x16x32_bf16(
              bq[j], af[i], acc[i][j], 0, 0, 0);
      __builtin_amdgcn_s_setprio(0);
      __builtin_amdgcn_s_barrier();

      // ---- phase ch=1: read A mf4..7 (B reused), compute acc[4..7][*] ----
      #pragma unroll
      for (int i = 0; i < 4; ++i) af[i] = *(const bf16x8*)(sbase + offA[4 + i]);
      stage(4 * t + 2 * ks + 7);
      __builtin_amdgcn_s_barrier();
      asm volatile("s_waitcnt lgkmcnt(0)" ::: "memory");
      __builtin_amdgcn_sched_barrier(0);
      __builtin_amdgcn_s_setprio(1);
      #pragma unroll
      for (int i = 0; i < 4; ++i)
        #pragma unroll
        for (int j = 0; j < 4; ++j)
          acc[4 + i][j] = __builtin_amdgcn_mfma_f32_16x16x32_bf16(
              bq[j], af[i], acc[4 + i][j], 0, 0, 0);
      __builtin_amdgcn_s_setprio(0);
      if (ks == 1) {                   // K-tile boundary: counted wait
        if (t < NT - 2) { asm volatile("s_waitcnt vmcnt(4)" ::: "memory"); }
        else            { asm volatile("s_waitcnt vmcnt(0)" ::: "memory"); }
      }
      __builtin_amdgcn_s_barrier();
    }
  }

  // ---- epilogue: D is transposed (operand swap) => lane holds 4 contiguous
  //      N-elems per (mf,nf): n = n0+wn+nf*16+kg*4+q, m = m0+wm+mf*16+l15 ----
  if constexpr (EPI == 0) {
    float4 bb[4];
    #pragma unroll
    for (int nf = 0; nf < 4; ++nf)
      bb[nf] = *(const float4*)(bias + n0 + wn + nf * 16 + kg * 4);
    #pragma unroll
    for (int mf = 0; mf < 8; ++mf) {
      bf16* orow = out + (size_t)(m0 + wm + mf * 16 + l15) * N + n0 + wn + kg * 4;
      #pragma unroll
      for (int nf = 0; nf < 4; ++nf) {
        bf16x4 o;
        o[0] = (bf16)gelu_fast(acc[mf][nf][0] + bb[nf].x);
        o[1] = (bf16)gelu_fast(acc[mf][nf][1] + bb[nf].y);
        o[2] = (bf16)gelu_fast(acc[mf][nf][2] + bb[nf].z);
        o[3] = (bf16)gelu_fast(acc[mf][nf][3] + bb[nf].w);
        *(bf16x4*)(orow + nf * 16) = o;
      }
    }
  } else {
    bf16* op = out + (size_t)zb * M * N;
    #pragma unroll
    for (int mf = 0; mf < 8; ++mf) {
      bf16* orow = op + (size_t)(m0 + wm + mf * 16 + l15) * N + n0 + wn + kg * 4;
      #pragma unroll
      for (int nf = 0; nf < 4; ++nf) {
        bf16x4 o;
        #pragma unroll
        for (int q = 0; q < 4; ++q) o[q] = (bf16)acc[mf][nf][q];
        *(bf16x4*)(orow + nf * 16) = o;
      }
    }
  }
}

// ---------------------------------------------------------------------------
extern "C" void kernel_launch(void* const* d_in, const int* in_sizes, int n_in,
                              void* d_out, int out_size, void* d_ws, size_t ws_size,
                              hipStream_t stream) {
  (void)in_sizes; (void)n_in; (void)out_size; (void)ws_size;

  const float* hidden = (const float*)d_in[0];
  const float* Wo     = (const float*)d_in[7];
  const float* bo     = (const float*)d_in[8];
  const float* ln1_g  = (const float*)d_in[9];
  const float* ln1_b  = (const float*)d_in[10];
  const float* Wi     = (const float*)d_in[11];
  const float* bi     = (const float*)d_in[12];
  const float* Wf     = (const float*)d_in[13];
  const float* bf_    = (const float*)d_in[14];
  const float* ln2_g  = (const float*)d_in[15];
  const float* ln2_b  = (const float*)d_in[16];
  float* out = (float*)d_out;

  // workspace layout (~98 MB)
  char* w = (char*)d_ws;
  float* cvec = (float*)w;
  size_t off = 4096;
  bf16* attn = (bf16*)(w + off); off += (size_t)MROWS * DM * 2;        // 12.6 MB
  bf16* h    = (bf16*)(w + off); off += (size_t)MROWS * DF * 2;        // 50.3 MB
  bf16* pre  = (bf16*)(w + off); off += (size_t)2 * MROWS * DM * 2;    // 25.2 MB
  bf16* Wib  = (bf16*)(w + off); off += (size_t)DF * DM * 2;           // 4.7 MB
  bf16* Wfb  = (bf16*)(w + off);                                       // 4.7 MB

  // allow 128 KiB dynamic LDS (no-op where not required); host-side, not a
  // stream op -> graph-capture safe; errors intentionally ignored
  static bool attr_done = false;
  if (!attr_done) {
    (void)hipFuncSetAttribute(reinterpret_cast<const void*>(&gemm8p<0>),
        hipFuncAttributeMaxDynamicSharedMemorySize, 131072);
    (void)hipFuncSetAttribute(reinterpret_cast<const void*>(&gemm8p<1>),
        hipFuncAttributeMaxDynamicSharedMemorySize, 131072);
    attr_done = true;
  }

  // 0. weight converts + cvec, one dispatch
  prep_kernel<<<dim3(CONV_BLOCKS + CVEC_BLOCKS), dim3(256), 0, stream>>>(
      Wi, Wf, Wib, Wfb, Wo, bo, cvec);

  // 1. attn = LN1(hidden + cvec)  (bf16)
  ln1_kernel<<<dim3(MROWS / 4), dim3(256), 0, stream>>>(hidden, cvec, ln1_g, ln1_b, attn);

  // 2. h = gelu(attn @ Wi^T + bi)      M=8192 N=3072 K=768 ; 32x12=384 blocks
  gemm8p<0><<<dim3(384), dim3(512), 131072, stream>>>(
      attn, Wib, bi, h, MROWS, DF, DM, DM, DF / 256, 384 / 8);

  // 3. pre[z] = h @ Wf^T (K-half z)    M=8192 N=768 K=3072, split-K=2
  //    32x3x2 = 192 blocks
  gemm8p<1><<<dim3(192), dim3(512), 131072, stream>>>(
      h, Wfb, nullptr, pre, MROWS, DM, DF, DF / 2, DM / 256, 192 / 8);

  // 4. out = LN2(pre0 + pre1 + bf + attn)
  ln2_kernel<<<dim3(MROWS / 4), dim3(256), 0, stream>>>(
      pre, pre + (size_t)MROWS * DM, bf_, attn, ln2_g, ln2_b, out);
}

// Round 2
// 224.639 us; speedup vs baseline: 1.0829x; 1.0829x over previous
//
#include <hip/hip_runtime.h>
#include <hip/hip_bf16.h>
#include <cstdint>
#include <cstddef>

// ---------------------------------------------------------------------------
// DebugBertLayer: reference overwrites q,k,v with 0.01 AFTER the projections,
// so ctx == 0.01 and ctx @ Wo.T + bo collapses to a per-channel constant
// c[i] = 0.01 * rowsum(Wo)[i] + bo[i].  Real work:
//   LN1(hidden + c) -> GEMM1(+GELU) -> GEMM2 (split-K=2) -> LN2(combine).
// R10: revert to the R8 128x128 / 2x2 x mfma_32x32x16 structure (R9's 256^2
// 8-phase regressed: 1 block/CU + 1.5/0.75-round grids + short K starved it).
// Two isolated fixes on top of R8:
//  (a) double-buffered stage-ahead: stage tile t+1 into buf^1 BEFORE
//      computing tile t; ONE __syncthreads per K-tile.  Overlaps the
//      global_load_lds latency with the tile-t MFMA work (T3-minimum).
//  (b) operand-swapped MFMA (mfma(b,a) => D transposed: regs hold contiguous
//      N) so the epilogue LDS transpose is 16x ds_write_b64 per lane instead
//      of 64x scalar ds_write_b16 -> kills the 4.9M bank-conflict cycles.
// ---------------------------------------------------------------------------

typedef __bf16 bf16;
typedef __attribute__((ext_vector_type(8))) __bf16 bf16x8;
typedef __attribute__((ext_vector_type(4))) __bf16 bf16x4;
typedef __attribute__((ext_vector_type(16))) float floatx16;

#define DM    768      // d_model
#define DF    3072     // d_ff
#define MROWS 8192     // B*S = 4*2048

#define N8          (DF * DM / 8)          // 294912 : 8-elem groups per weight
#define CONV_BLOCKS (2 * N8 / 256)         // 2304 convert blocks
#define CVEC_BLOCKS (DM / 4)               // 192 blocks, wave per row

__device__ __forceinline__ void gl2lds16(const void* gp, void* lp) {
  __builtin_amdgcn_global_load_lds(
      (__attribute__((address_space(1))) void*)(void*)gp,
      (__attribute__((address_space(3))) void*)lp,
      16, 0, 0);
}

// fast GELU (tanh form): x * sigmoid(1.5958*(x + 0.044715*x^3))
__device__ __forceinline__ float gelu_fast(float x) {
  float x2 = x * x;
  float m  = x * __builtin_fmaf(-0.1029641f, x2, -2.3025851f);
  float e  = __builtin_amdgcn_exp2f(m);
  return x * __builtin_amdgcn_rcpf(1.0f + e);
}

// ---------------------------------------------------------------------------
// prep: blocks [0, CONV_BLOCKS) convert Wi/Wf fp32->bf16 (8 elem/thread);
//       blocks [CONV_BLOCKS, +CVEC_BLOCKS) compute cvec, one wave per row.
// ---------------------------------------------------------------------------
__global__ __launch_bounds__(256)
void prep_kernel(const float* __restrict__ Wi, const float* __restrict__ Wf,
                 bf16* __restrict__ Wib, bf16* __restrict__ Wfb,
                 const float* __restrict__ Wo, const float* __restrict__ bo,
                 float* __restrict__ cvec) {
  if (blockIdx.x < CONV_BLOCKS) {
    int i = blockIdx.x * 256 + threadIdx.x;
    const float* src = (i < N8) ? Wi : Wf;
    bf16* dst        = (i < N8) ? Wib : Wfb;
    int k            = (i < N8) ? i : i - N8;
    const float4* p = (const float4*)(src + (size_t)k * 8);
    float4 x = p[0], y = p[1];
    bf16x8 o;
    o[0]=(bf16)x.x; o[1]=(bf16)x.y; o[2]=(bf16)x.z; o[3]=(bf16)x.w;
    o[4]=(bf16)y.x; o[5]=(bf16)y.y; o[6]=(bf16)y.z; o[7]=(bf16)y.w;
    *(bf16x8*)(dst + (size_t)k * 8) = o;
  } else {
    int row  = (blockIdx.x - CONV_BLOCKS) * 4 + (threadIdx.x >> 6);
    int lane = threadIdx.x & 63;
    const float4* r = (const float4*)(Wo + (size_t)row * DM);
    float s = 0.f;
    #pragma unroll
    for (int t = 0; t < 3; ++t) {
      float4 v = r[lane + t * 64];
      s += v.x + v.y + v.z + v.w;
    }
    #pragma unroll
    for (int o = 32; o > 0; o >>= 1) s += __shfl_xor(s, o);
    if (lane == 0) cvec[row] = 0.01f * s + bo[row];
  }
}

// ---------------------------------------------------------------------------
// attn_out[row] = LN(hidden[row] + cvec) -> bf16.  4 rows/block (wave each).
// ---------------------------------------------------------------------------
__global__ __launch_bounds__(256)
void ln1_kernel(const float* __restrict__ hid, const float* __restrict__ cvec,
                const float* __restrict__ g, const float* __restrict__ b,
                bf16* __restrict__ out) {
  int row  = blockIdx.x * 4 + (threadIdx.x >> 6);
  int lane = threadIdx.x & 63;
  const float4* hrow = (const float4*)(hid + (size_t)row * DM);
  const float4* cv4  = (const float4*)cvec;
  float x[12];
  float s = 0.f, sq = 0.f;
  #pragma unroll
  for (int t = 0; t < 3; ++t) {
    int c = lane + t * 64;
    float4 v = hrow[c];
    float4 cc = cv4[c];
    float x0 = v.x + cc.x, x1 = v.y + cc.y, x2 = v.z + cc.z, x3 = v.w + cc.w;
    x[t*4+0] = x0; x[t*4+1] = x1; x[t*4+2] = x2; x[t*4+3] = x3;
    s  += x0 + x1 + x2 + x3;
    sq += x0*x0 + x1*x1 + x2*x2 + x3*x3;
  }
  #pragma unroll
  for (int o = 32; o > 0; o >>= 1) { s += __shfl_xor(s, o); sq += __shfl_xor(sq, o); }
  float mu  = s * (1.0f / DM);
  float var = sq * (1.0f / DM) - mu * mu;
  float inv = rsqrtf(var + 1e-12f);
  const float4* g4 = (const float4*)g;
  const float4* b4 = (const float4*)b;
  #pragma unroll
  for (int t = 0; t < 3; ++t) {
    int c = lane + t * 64;
    float4 gg = g4[c], bb = b4[c];
    bf16x4 o4;
    o4[0] = (bf16)((x[t*4+0] - mu) * inv * gg.x + bb.x);
    o4[1] = (bf16)((x[t*4+1] - mu) * inv * gg.y + bb.y);
    o4[2] = (bf16)((x[t*4+2] - mu) * inv * gg.z + bb.z);
    o4[3] = (bf16)((x[t*4+3] - mu) * inv * gg.w + bb.w);
    *(bf16x4*)(out + (size_t)row * DM + c * 4) = o4;
  }
}

// ---------------------------------------------------------------------------
// out[row] = LN( p0 + p1 + bias + attn )   (bf16 partials) -> fp32 out
// ---------------------------------------------------------------------------
__global__ __launch_bounds__(256)
void ln2_kernel(const bf16* __restrict__ p0, const bf16* __restrict__ p1,
                const float* __restrict__ bias, const bf16* __restrict__ attn,
                const float* __restrict__ g, const float* __restrict__ b,
                float* __restrict__ out) {
  int row  = blockIdx.x * 4 + (threadIdx.x >> 6);
  int lane = threadIdx.x & 63;
  const bf16* r0 = p0 + (size_t)row * DM;
  const bf16* r1 = p1 + (size_t)row * DM;
  const bf16* ar = attn + (size_t)row * DM;
  const float4* bi4 = (const float4*)bias;
  float x[12];
  float s = 0.f, sq = 0.f;
  #pragma unroll
  for (int t = 0; t < 3; ++t) {
    int c = lane + t * 64;
    bf16x4 a = *(const bf16x4*)(r0 + c * 4);
    bf16x4 d = *(const bf16x4*)(r1 + c * 4);
    bf16x4 rv = *(const bf16x4*)(ar + c * 4);
    float4 bb = bi4[c];
    float x0 = (float)a[0] + (float)d[0] + bb.x + (float)rv[0];
    float x1 = (float)a[1] + (float)d[1] + bb.y + (float)rv[1];
    float x2 = (float)a[2] + (float)d[2] + bb.z + (float)rv[2];
    float x3 = (float)a[3] + (float)d[3] + bb.w + (float)rv[3];
    x[t*4+0] = x0; x[t*4+1] = x1; x[t*4+2] = x2; x[t*4+3] = x3;
    s  += x0 + x1 + x2 + x3;
    sq += x0*x0 + x1*x1 + x2*x2 + x3*x3;
  }
  #pragma unroll
  for (int o = 32; o > 0; o >>= 1) { s += __shfl_xor(s, o); sq += __shfl_xor(sq, o); }
  float mu  = s * (1.0f / DM);
  float var = sq * (1.0f / DM) - mu * mu;
  float inv = rsqrtf(var + 1e-12f);
  const float4* g4 = (const float4*)g;
  const float4* b4 = (const float4*)b;
  float4* orow = (float4*)(out + (size_t)row * DM);
  #pragma unroll
  for (int t = 0; t < 3; ++t) {
    int c = lane + t * 64;
    float4 gg = g4[c], bb = b4[c];
    float4 o;
    o.x = (x[t*4+0] - mu) * inv * gg.x + bb.x;
    o.y = (x[t*4+1] - mu) * inv * gg.y + bb.y;
    o.z = (x[t*4+2] - mu) * inv * gg.z + bb.z;
    o.w = (x[t*4+3] - mu) * inv * gg.w + bb.w;
    orow[c] = o;
  }
}

// ---------------------------------------------------------------------------
// NT bf16 MFMA GEMM, 128x128 tile, BK=64, double-buffered.  4 waves, each
// 64x64 as 2x2 of v_mfma_f32_32x32x16_bf16 with OPERANDS SWAPPED:
//   acc = mfma(b_frag, a_frag, acc)  =>  D transposed:
//   m = l31 (within 32-subtile), n = (reg&3) + 8*(reg>>2) + 4*lhi.
// Consecutive regs = consecutive N -> epilogue writes bf16x4 to LDS (b64),
// then the same coalesced bf16x8 global stores as R8.
// K-loop: stage(t+1 -> buf^1) issued before compute(t, buf); one
// __syncthreads per K-tile (its implicit vmcnt drain completes t+1's loads
// after they've overlapped with tile-t compute).
// Grid (ygroups, xz): id%8 == y%8 -> same-m blocks share an XCD.
// ---------------------------------------------------------------------------
#define BM 128
#define BN 128
#define BK 64
#define ES 136   // epilogue LDS row stride in bf16 (272 B, 16B-aligned)

template <int EPI>
__global__ __launch_bounds__(256)
void gemm_nt(const bf16* __restrict__ A, const bf16* __restrict__ B,
             const float* __restrict__ bias,
             bf16* __restrict__ out, int M, int N, int K, int ksplit, int NB) {
  __shared__ __align__(16) unsigned char smem[65536];  // 2 x (16K A + 16K B)

  const int tid   = threadIdx.x;
  const int wave  = tid >> 6;
  const int lane  = tid & 63;
  const int l31   = lane & 31;
  const int lhi   = lane >> 5;          // k-half selector for 32x32 frags
  const int xorv  = lane & 7;           // reader-side swizzle key (row&7)

  const int ygrp = blockIdx.x;          // m-row-group (fast index -> XCD key)
  const int xz   = blockIdx.y;
  const int xb   = xz % NB;             // n-block
  const int zb   = xz / NB;             // k-split

  const int m0 = ygrp * BM;
  const int n0 = xb * BN;
  const int wm = (wave >> 1) * 64;
  const int wn = (wave & 1) * 64;

  const int kbeg = zb * ksplit;
  const int NT   = ksplit / BK;

  floatx16 acc[2][2] = {};
  const bf16* Ablk = A + (size_t)m0 * K;
  const bf16* Bblk = B + (size_t)n0 * K;

  // stage one BKx(BM,BN) tile into buffer bf (XOR-swizzled source chunks,
  // linear LDS dest as global_load_lds requires)
  auto stage = [&](int bf, int kk) {
    bf16* la = (bf16*)(smem + bf * 32768);
    bf16* lb = la + BM * BK;
    #pragma unroll
    for (int i = 0; i < 4; ++i) {
      int ci  = tid + 256 * i;
      int r   = ci >> 3;
      int c_g = (ci & 7) ^ (r & 7);     // swizzled source chunk
      gl2lds16(Ablk + (size_t)r * K + kk + c_g * 8, la + ci * 8);
      gl2lds16(Bblk + (size_t)r * K + kk + c_g * 8, lb + ci * 8);
    }
  };

  stage(0, kbeg);
  int buf = 0;
  for (int t = 0; t < NT; ++t) {
    __syncthreads();                    // tile t landed in buf (vmcnt drain)
    if (t + 1 < NT) stage(buf ^ 1, kbeg + (t + 1) * BK);   // overlap w/ MFMA
    const bf16* la = (const bf16*)(smem + buf * 32768);
    const bf16* lb = la + BM * BK;
    #pragma unroll
    for (int ks = 0; ks < BK; ks += 16) {
      const int cs = ((ks >> 3) + lhi) ^ xorv;   // swizzled chunk to read
      bf16x8 af[2], bfr[2];
      #pragma unroll
      for (int i = 0; i < 2; ++i)
        af[i] = *(const bf16x8*)&la[(wm + i * 32 + l31) * BK + cs * 8];
      #pragma unroll
      for (int j = 0; j < 2; ++j)
        bfr[j] = *(const bf16x8*)&lb[(wn + j * 32 + l31) * BK + cs * 8];
      #pragma unroll
      for (int i = 0; i < 2; ++i)
        #pragma unroll
        for (int j = 0; j < 2; ++j)
          acc[i][j] = __builtin_amdgcn_mfma_f32_32x32x16_bf16(
              bfr[j], af[i], acc[i][j], 0, 0, 0);   // swapped: D transposed
    }
    buf ^= 1;
  }
  __syncthreads();   // all compute reads done before epilogue reuses smem

  // ---- epilogue: D^T layout => per-lane bf16x4 LDS writes, then the same
  //      coalesced bf16x8 global stores ----
  bf16* eb = (bf16*)smem;

  #pragma unroll
  for (int i = 0; i < 2; ++i) {
    #pragma unroll
    for (int j = 0; j < 2; ++j) {
      const int rowb = wm + i * 32 + l31;         // M within tile
      const int colb = wn + j * 32 + 4 * lhi;     // N within tile
      #pragma unroll
      for (int rq = 0; rq < 4; ++rq) {
        const int col = colb + rq * 8;
        bf16x4 o;
        if constexpr (EPI == 0) {
          float4 bb = *(const float4*)(bias + n0 + col);
          o[0] = (bf16)gelu_fast(acc[i][j][rq*4+0] + bb.x);
          o[1] = (bf16)gelu_fast(acc[i][j][rq*4+1] + bb.y);
          o[2] = (bf16)gelu_fast(acc[i][j][rq*4+2] + bb.z);
          o[3] = (bf16)gelu_fast(acc[i][j][rq*4+3] + bb.w);
        } else {
          o[0] = (bf16)acc[i][j][rq*4+0];
          o[1] = (bf16)acc[i][j][rq*4+1];
          o[2] = (bf16)acc[i][j][rq*4+2];
          o[3] = (bf16)acc[i][j][rq*4+3];
        }
        *(bf16x4*)&eb[rowb * ES + col] = o;
      }
    }
  }
  __syncthreads();

  bf16* outp = out + (EPI == 1 ? (size_t)zb * M * N : 0);
  const int rsub = tid >> 4;
  const int csub = (tid & 15) * 8;
  #pragma unroll
  for (int c = 0; c < 8; ++c) {
    int row = c * 16 + rsub;
    bf16x8 v = *(const bf16x8*)&eb[row * ES + csub];
    *(bf16x8*)&outp[(size_t)(m0 + row) * N + n0 + csub] = v;
  }
}

// ---------------------------------------------------------------------------
extern "C" void kernel_launch(void* const* d_in, const int* in_sizes, int n_in,
                              void* d_out, int out_size, void* d_ws, size_t ws_size,
                              hipStream_t stream) {
  (void)in_sizes; (void)n_in; (void)out_size; (void)ws_size;

  const float* hidden = (const float*)d_in[0];
  const float* Wo     = (const float*)d_in[7];
  const float* bo     = (const float*)d_in[8];
  const float* ln1_g  = (const float*)d_in[9];
  const float* ln1_b  = (const float*)d_in[10];
  const float* Wi     = (const float*)d_in[11];
  const float* bi     = (const float*)d_in[12];
  const float* Wf     = (const float*)d_in[13];
  const float* bf_    = (const float*)d_in[14];
  const float* ln2_g  = (const float*)d_in[15];
  const float* ln2_b  = (const float*)d_in[16];
  float* out = (float*)d_out;

  // workspace layout (~98 MB)
  char* w = (char*)d_ws;
  float* cvec = (float*)w;
  size_t off = 4096;
  bf16* attn = (bf16*)(w + off); off += (size_t)MROWS * DM * 2;        // 12.6 MB
  bf16* h    = (bf16*)(w + off); off += (size_t)MROWS * DF * 2;        // 50.3 MB
  bf16* pre  = (bf16*)(w + off); off += (size_t)2 * MROWS * DM * 2;    // 25.2 MB
  bf16* Wib  = (bf16*)(w + off); off += (size_t)DF * DM * 2;           // 4.7 MB
  bf16* Wfb  = (bf16*)(w + off);                                       // 4.7 MB

  // 0. weight converts + cvec, one dispatch
  prep_kernel<<<dim3(CONV_BLOCKS + CVEC_BLOCKS), dim3(256), 0, stream>>>(
      Wi, Wf, Wib, Wfb, Wo, bo, cvec);

  // 1. attn = LN1(hidden + cvec)  (bf16)
  ln1_kernel<<<dim3(MROWS / 4), dim3(256), 0, stream>>>(hidden, cvec, ln1_g, ln1_b, attn);

  // 2. h = gelu(attn @ Wi^T + bi)      M=8192 N=3072 K=768
  gemm_nt<0><<<dim3(MROWS / BM, DF / BN), dim3(256), 0, stream>>>(
      attn, Wib, bi, h, MROWS, DF, DM, DM, DF / BN);

  // 3. pre[z] = h @ Wf^T (K-half z)    M=8192 N=768 K=3072, split-K=2
  gemm_nt<1><<<dim3(MROWS / BM, (DM / BN) * 2), dim3(256), 0, stream>>>(
      h, Wfb, nullptr, pre, MROWS, DM, DF, DF / 2, DM / BN);

  // 4. out = LN2(pre0 + pre1 + bf + attn)
  ln2_kernel<<<dim3(MROWS / 4), dim3(256), 0, stream>>>(
      pre, pre + (size_t)MROWS * DM, bf_, attn, ln2_g, ln2_b, out);
}